// Round 4
// baseline (183.777 us; speedup 1.0000x reference)
//
#include <hip/hip_runtime.h>

#define W 512
#define NPIX (512*512)

typedef float v2f __attribute__((ext_vector_type(2)));

__device__ __forceinline__ float fexp2(float x) {
#if __has_builtin(__builtin_amdgcn_exp2f)
    return __builtin_amdgcn_exp2f(x);
#else
    return __expf(x * 0.6931471805599453f);
#endif
}
__device__ __forceinline__ v2f vfma(v2f a, v2f b, v2f c) {
    return __builtin_elementwise_fma(a, b, c);
}
__device__ __forceinline__ v2f bc2(float x) { v2f r; r.x = x; r.y = x; return r; }

// ---------------- fused prep: 9x9 separable box via LDS; emits interleaved
// XYb=(Xb,yb), XDd=(Xd,(y-yb)-Xd); also reduces global min/max of y via
// monotone-int-key atomicMax (poison 0xAA is a negative int => safe init). ----
__global__ __launch_bounds__(512) void k_prep(const float* __restrict__ X,
                                              const float* __restrict__ y,
                                              float2* __restrict__ XYb,
                                              float2* __restrict__ XDd,
                                              int* __restrict__ mm) {
    __shared__ float sX[16][72], sY[16][72];
    __shared__ float rX[16][64], rY[16][64];
    int tx = threadIdx.x, ty = threadIdx.y;
    int t = ty * 64 + tx;
    int c0 = blockIdx.x * 64, r0 = blockIdx.y * 8;
    for (int i = t; i < 16 * 72; i += 512) {
        int rr = i / 72, cc = i - rr * 72;
        int gr = r0 - 4 + rr, gc = c0 - 4 + cc;
        bool ok = ((unsigned)gr < 512u) & ((unsigned)gc < 512u);
        sX[rr][cc] = ok ? X[gr * W + gc] : 0.f;
        sY[rr][cc] = ok ? y[gr * W + gc] : 0.f;
    }
    __syncthreads();
    for (int i = t; i < 16 * 64; i += 512) {
        int rr = i >> 6, cc = i & 63;
        float ax = 0.f, ay = 0.f;
#pragma unroll
        for (int j = 0; j < 9; ++j) { ax += sX[rr][cc + j]; ay += sY[rr][cc + j]; }
        rX[rr][cc] = ax; rY[rr][cc] = ay;
    }
    __syncthreads();
    float ax = 0.f, ay = 0.f;
#pragma unroll
    for (int j = 0; j < 9; ++j) { ax += rX[ty + j][tx]; ay += rY[ty + j][tx]; }
    const float inv81 = 1.0f / 81.0f;
    float xb = ax * inv81, yb = ay * inv81;
    float xv = sX[ty + 4][tx + 4], yv = sY[ty + 4][tx + 4];
    float xd = xv - xb;
    int p = (r0 + ty) * W + (c0 + tx);
    XYb[p] = make_float2(xb, yb);
    XDd[p] = make_float2(xd, (yv - yb) - xd);

    // global min/max of y: keys are positive ints for positive floats
    int kmx = __float_as_int(yv);              // max key
    int kmn = 0x7FFFFFFF - kmx;                // min key (also positive)
#pragma unroll
    for (int m = 32; m; m >>= 1) {
        kmx = max(kmx, __shfl_xor(kmx, m));
        kmn = max(kmn, __shfl_xor(kmn, m));
    }
    if (tx == 0) { atomicMax(&mm[0], kmx); atomicMax(&mm[1], kmn); }
}

// ---------------- main fused kernel: 2 vertical px/thread, packed-f32 math ----
__global__ __launch_bounds__(256) void k_main(const float2* __restrict__ XYb,
                                              const float2* __restrict__ XDd,
                                              const int* __restrict__ mm,
                                              const float* __restrict__ r,
                                              float* __restrict__ out) {
    __shared__ float sbx[19];   // row spatial weights, 19x19 filter
    __shared__ float sdy[5];    // row spatial weights, 5x9 filter
    int tx = threadIdx.x, ty = threadIdx.y;
    int t = ty * 64 + tx;
    if (t < 19)      { int d = t - 9;      sbx[t]      = __expf(-(float)(d * d) / 8145.0625f); }
    else if (t < 24) { int d = t - 19 - 2; sdy[t - 19] = __expf(-(float)(d * d) / 126.5625f); }
    __syncthreads();

    float ymax = __int_as_float(mm[0]);
    float ymin = __int_as_float(0x7FFFFFFF - mm[1]);
    float sigma = r[0] * (ymax - ymin);
    float hh = 0.5f * sigma;
    float k2 = -1.4426950408889634f / (hh * hh);   // w_range = 2^(u^2*k2)
    v2f k2v = bc2(k2);

    int c  = blockIdx.x * 64 + tx;
    int h0 = (blockIdx.y * 4 + ty) * 2;            // rows h0, h0+1

    // chunk mapping: output col -> owning chunk after overlap-trim
    int chunk = (c == 0) ? 0 : (c - 1) / 62;
    if (chunk > 8) chunk = 8;
    int s = 62 * chunk;
    int e = (chunk == 8) ? 512 : (s + 64);

    // column exponents (log2-domain spatial) with chunk mask folded in
    const float ksb = -1.4426950408889634f / 8145.0625f;
    const float ksd = -1.4426950408889634f / 126.5625f;
    float cc[19];
#pragma unroll
    for (int j = 0; j < 19; ++j) {
        int nc = c - 9 + j, d = j - 9;
        cc[j] = ((nc >= s) & (nc < e)) ? ksb * (float)(d * d) : -1e30f;
    }
    float ccd[9];
#pragma unroll
    for (int j = 0; j < 9; ++j) {
        int nc = c - 4 + j, d = j - 4;
        ccd[j] = ((nc >= s) & (nc < e)) ? ksd * (float)(d * d) : -1e30f;
    }

    int p0 = h0 * W + c;
    v2f Xc2; Xc2.x = XYb[p0].x; Xc2.y = XYb[p0 + W].x;
    v2f Xd2; Xd2.x = XDd[p0].x; Xd2.y = XDd[p0 + W].x;

    // ---- base pass: 19x19 bilateral guided-filter stats, packed 2 px ----
    v2f sw = bc2(0.f), swx = bc2(0.f), swy = bc2(0.f), swxx = bc2(0.f), swxy = bc2(0.f);
#pragma unroll 1
    for (int nh = h0 - 9; nh <= h0 + 10; ++nh) {
        if ((unsigned)nh >= 512u) continue;          // wave-uniform
        int dy0 = nh - h0;                           // -9..10
        const float2* xr = XYb + (nh * W + c);
        v2f rs = bc2(0.f), rsx = bc2(0.f), rsy = bc2(0.f), rsxx = bc2(0.f), rsxy = bc2(0.f);
#pragma unroll
        for (int j = 0; j < 19; ++j) {
            float2 v = xr[j - 9];
            v2f xv = bc2(v.x), yv = bc2(v.y);
            v2f u = xv - Xc2;
            v2f a = vfma(u * k2v, u, bc2(cc[j]));
            v2f w; w.x = fexp2(a.x); w.y = fexp2(a.y);
            rs = rs + w;
            rsx = vfma(w, xv, rsx);
            rsy = vfma(w, yv, rsy);
            v2f tt = w * xv;
            rsxx = vfma(tt, xv, rsxx);
            rsxy = vfma(tt, yv, rsxy);
        }
        v2f ey;
        ey.x = (dy0 <= 9)  ? sbx[dy0 + 9] : 0.f;
        ey.y = (dy0 >= -8) ? sbx[dy0 + 8] : 0.f;
        sw   = vfma(ey, rs,   sw);
        swx  = vfma(ey, rsx,  swx);
        swy  = vfma(ey, rsy,  swy);
        swxx = vfma(ey, rsxx, swxx);
        swxy = vfma(ey, rsxy, swxy);
    }

    // ---- detail pass: 5(h)x9(w) bilateral on residuals, packed 2 px ----
    v2f swd = bc2(0.f), sv = bc2(0.f);
#pragma unroll 1
    for (int nh = h0 - 2; nh <= h0 + 3; ++nh) {
        if ((unsigned)nh >= 512u) continue;
        int dyd = nh - h0;                           // -2..3
        const float2* dr = XDd + (nh * W + c);
        v2f rs = bc2(0.f), rv = bc2(0.f);
#pragma unroll
        for (int j = 0; j < 9; ++j) {
            float2 v = dr[j - 4];
            v2f xd = bc2(v.x), dv = bc2(v.y);
            v2f u = xd - Xd2;
            v2f a = vfma(u * k2v, u, bc2(ccd[j]));
            v2f w; w.x = fexp2(a.x); w.y = fexp2(a.y);
            rs = rs + w;
            rv = vfma(w, dv, rv);
        }
        v2f ey;
        ey.x = (dyd <= 2)  ? sdy[dyd + 2] : 0.f;
        ey.y = (dyd >= -1) ? sdy[dyd + 1] : 0.f;
        swd = vfma(ey, rs, swd);
        sv  = vfma(ey, rv, sv);
    }

    // ---- combine & store both pixels ----
    v2f inv; inv.x = 1.0f / sw.x; inv.y = 1.0f / sw.y;
    v2f mx = swx * inv, my = swy * inv;
    v2f varx = vfma(-mx, mx, swxx * inv);
    v2f cov  = vfma(-mx, my, swxy * inv);
    v2f A; A.x = cov.x / (varx.x + 1e-6f); A.y = cov.y / (varx.y + 1e-6f);
    v2f b = my - A * mx;
    v2f Xb2; Xb2.x = Xc2.x; Xb2.y = Xc2.y;
    v2f bd; bd.x = sv.x / swd.x; bd.y = sv.y / swd.y;
    v2f res = A * Xb2 + b + Xd2 + bd;
    out[p0]     = res.x;
    out[p0 + W] = res.y;
}

extern "C" void kernel_launch(void* const* d_in, const int* in_sizes, int n_in,
                              void* d_out, int out_size, void* d_ws, size_t ws_size,
                              hipStream_t stream) {
    const float* X = (const float*)d_in[0];
    const float* y = (const float*)d_in[1];
    const float* r = (const float*)d_in[2];
    float* out = (float*)d_out;
    float* wsf = (float*)d_ws;

    int* mm = (int*)(wsf + 32);                            // 2 ints (poison-safe keys)
    float2* XYb = (float2*)(wsf + 1024) + 256;             // guarded
    float2* XDd = XYb + NPIX + 512;                        // guarded

    k_prep<<<dim3(8, 64), dim3(64, 8), 0, stream>>>(X, y, XYb, XDd, mm);
    k_main<<<dim3(8, 64), dim3(64, 4), 0, stream>>>(XYb, XDd, mm, r, out);
}

// Round 5
// 92.461 us; speedup vs baseline: 1.9876x; 1.9876x over previous
//
#include <hip/hip_runtime.h>

#define W 512
#define NPIX (512*512)

typedef float v2f __attribute__((ext_vector_type(2)));

__device__ __forceinline__ float fexp2(float x) {
#if __has_builtin(__builtin_amdgcn_exp2f)
    return __builtin_amdgcn_exp2f(x);
#else
    return __expf(x * 0.6931471805599453f);
#endif
}
__device__ __forceinline__ v2f vfma(v2f a, v2f b, v2f c) {
    return __builtin_elementwise_fma(a, b, c);
}
__device__ __forceinline__ v2f bc2(float x) { v2f r; r.x = x; r.y = x; return r; }

// ---------------- fused prep: 9x9 separable box via LDS; emits interleaved
// XYb=(Xb,yb), XDd=(Xd,(y-yb)-Xd); per-block y-min/max partial (NO atomics —
// same-address cross-XCD atomics serialize ~25ns each, R4 lost 90us to that). ----
__global__ __launch_bounds__(512) void k_prep(const float* __restrict__ X,
                                              const float* __restrict__ y,
                                              float2* __restrict__ XYb,
                                              float2* __restrict__ XDd,
                                              float2* __restrict__ partial) {
    __shared__ float sX[16][72], sY[16][72];
    __shared__ float rX[16][64], rY[16][64];
    __shared__ float wmn[8], wmx[8];
    int tx = threadIdx.x, ty = threadIdx.y;
    int t = ty * 64 + tx;
    int c0 = blockIdx.x * 64, r0 = blockIdx.y * 8;
    for (int i = t; i < 16 * 72; i += 512) {
        int rr = i / 72, cc = i - rr * 72;
        int gr = r0 - 4 + rr, gc = c0 - 4 + cc;
        bool ok = ((unsigned)gr < 512u) & ((unsigned)gc < 512u);
        sX[rr][cc] = ok ? X[gr * W + gc] : 0.f;
        sY[rr][cc] = ok ? y[gr * W + gc] : 0.f;
    }
    __syncthreads();
    for (int i = t; i < 16 * 64; i += 512) {
        int rr = i >> 6, cc = i & 63;
        float ax = 0.f, ay = 0.f;
#pragma unroll
        for (int j = 0; j < 9; ++j) { ax += sX[rr][cc + j]; ay += sY[rr][cc + j]; }
        rX[rr][cc] = ax; rY[rr][cc] = ay;
    }
    __syncthreads();
    float ax = 0.f, ay = 0.f;
#pragma unroll
    for (int j = 0; j < 9; ++j) { ax += rX[ty + j][tx]; ay += rY[ty + j][tx]; }
    const float inv81 = 1.0f / 81.0f;
    float xb = ax * inv81, yb = ay * inv81;
    float xv = sX[ty + 4][tx + 4], yv = sY[ty + 4][tx + 4];
    float xd = xv - xb;
    int p = (r0 + ty) * W + (c0 + tx);
    XYb[p] = make_float2(xb, yb);
    XDd[p] = make_float2(xd, (yv - yb) - xd);

    // per-block min/max of y (each interior pixel owned by exactly one thread)
    float mn = yv, mx = yv;
#pragma unroll
    for (int m = 32; m; m >>= 1) {
        mn = fminf(mn, __shfl_xor(mn, m));
        mx = fmaxf(mx, __shfl_xor(mx, m));
    }
    if (tx == 0) { wmn[ty] = mn; wmx[ty] = mx; }
    __syncthreads();
    if (t == 0) {
#pragma unroll
        for (int j = 1; j < 8; ++j) { mn = fminf(mn, wmn[j]); mx = fmaxf(mx, wmx[j]); }
        partial[blockIdx.y * 8 + blockIdx.x] = make_float2(mn, mx);
    }
}

// ---------------- main fused kernel: 2 vertical px/thread, packed-f32 math ----
__global__ __launch_bounds__(256) void k_main(const float2* __restrict__ XYb,
                                              const float2* __restrict__ XDd,
                                              const float2* __restrict__ partial,
                                              const float* __restrict__ r,
                                              float* __restrict__ out) {
    __shared__ float sbx[19];   // row spatial weights, 19x19 filter
    __shared__ float sdy[5];    // row spatial weights, 5x9 filter
    __shared__ float2 red[256];
    int tx = threadIdx.x, ty = threadIdx.y;
    int t = ty * 64 + tx;
    if (t < 19)      { int d = t - 9;      sbx[t]      = __expf(-(float)(d * d) / 8145.0625f); }
    else if (t < 24) { int d = t - 19 - 2; sdy[t - 19] = __expf(-(float)(d * d) / 126.5625f); }

    // reduce the 512 per-block partials to global min/max (all L2 hits)
    {
        float2 p0 = partial[t], p1 = partial[t + 256];
        red[t] = make_float2(fminf(p0.x, p1.x), fmaxf(p0.y, p1.y));
    }
    __syncthreads();
    for (int off = 128; off > 0; off >>= 1) {
        if (t < off) {
            red[t].x = fminf(red[t].x, red[t + off].x);
            red[t].y = fmaxf(red[t].y, red[t + off].y);
        }
        __syncthreads();
    }
    float sigma = r[0] * (red[0].y - red[0].x);
    float hh = 0.5f * sigma;
    float k2 = -1.4426950408889634f / (hh * hh);   // w_range = 2^(u^2*k2)
    v2f k2v = bc2(k2);

    int c  = blockIdx.x * 64 + tx;
    int h0 = (blockIdx.y * 4 + ty) * 2;            // rows h0, h0+1

    // chunk mapping: output col -> owning chunk after overlap-trim
    int chunk = (c == 0) ? 0 : (c - 1) / 62;
    if (chunk > 8) chunk = 8;
    int s = 62 * chunk;
    int e = (chunk == 8) ? 512 : (s + 64);

    // column exponents (log2-domain spatial) with chunk mask folded in
    const float ksb = -1.4426950408889634f / 8145.0625f;
    const float ksd = -1.4426950408889634f / 126.5625f;
    float cc[19];
#pragma unroll
    for (int j = 0; j < 19; ++j) {
        int nc = c - 9 + j, d = j - 9;
        cc[j] = ((nc >= s) & (nc < e)) ? ksb * (float)(d * d) : -1e30f;
    }
    float ccd[9];
#pragma unroll
    for (int j = 0; j < 9; ++j) {
        int nc = c - 4 + j, d = j - 4;
        ccd[j] = ((nc >= s) & (nc < e)) ? ksd * (float)(d * d) : -1e30f;
    }

    int p0 = h0 * W + c;
    v2f Xc2; Xc2.x = XYb[p0].x; Xc2.y = XYb[p0 + W].x;
    v2f Xd2; Xd2.x = XDd[p0].x; Xd2.y = XDd[p0 + W].x;

    // ---- base pass: 19x19 bilateral guided-filter stats, packed 2 px ----
    v2f sw = bc2(0.f), swx = bc2(0.f), swy = bc2(0.f), swxx = bc2(0.f), swxy = bc2(0.f);
#pragma unroll 1
    for (int nh = h0 - 9; nh <= h0 + 10; ++nh) {
        if ((unsigned)nh >= 512u) continue;          // wave-uniform
        int dy0 = nh - h0;                           // -9..10
        const float2* xr = XYb + (nh * W + c);
        v2f rs = bc2(0.f), rsx = bc2(0.f), rsy = bc2(0.f), rsxx = bc2(0.f), rsxy = bc2(0.f);
#pragma unroll
        for (int j = 0; j < 19; ++j) {
            float2 v = xr[j - 9];
            v2f xv = bc2(v.x), yv = bc2(v.y);
            v2f u = xv - Xc2;
            v2f a = vfma(u * k2v, u, bc2(cc[j]));
            v2f w; w.x = fexp2(a.x); w.y = fexp2(a.y);
            rs = rs + w;
            rsx = vfma(w, xv, rsx);
            rsy = vfma(w, yv, rsy);
            v2f tt = w * xv;
            rsxx = vfma(tt, xv, rsxx);
            rsxy = vfma(tt, yv, rsxy);
        }
        v2f ey;
        ey.x = (dy0 <= 9)  ? sbx[dy0 + 9] : 0.f;
        ey.y = (dy0 >= -8) ? sbx[dy0 + 8] : 0.f;
        sw   = vfma(ey, rs,   sw);
        swx  = vfma(ey, rsx,  swx);
        swy  = vfma(ey, rsy,  swy);
        swxx = vfma(ey, rsxx, swxx);
        swxy = vfma(ey, rsxy, swxy);
    }

    // ---- detail pass: 5(h)x9(w) bilateral on residuals, packed 2 px ----
    v2f swd = bc2(0.f), sv = bc2(0.f);
#pragma unroll 1
    for (int nh = h0 - 2; nh <= h0 + 3; ++nh) {
        if ((unsigned)nh >= 512u) continue;
        int dyd = nh - h0;                           // -2..3
        const float2* dr = XDd + (nh * W + c);
        v2f rs = bc2(0.f), rv = bc2(0.f);
#pragma unroll
        for (int j = 0; j < 9; ++j) {
            float2 v = dr[j - 4];
            v2f xd = bc2(v.x), dv = bc2(v.y);
            v2f u = xd - Xd2;
            v2f a = vfma(u * k2v, u, bc2(ccd[j]));
            v2f w; w.x = fexp2(a.x); w.y = fexp2(a.y);
            rs = rs + w;
            rv = vfma(w, dv, rv);
        }
        v2f ey;
        ey.x = (dyd <= 2)  ? sdy[dyd + 2] : 0.f;
        ey.y = (dyd >= -1) ? sdy[dyd + 1] : 0.f;
        swd = vfma(ey, rs, swd);
        sv  = vfma(ey, rv, sv);
    }

    // ---- combine & store both pixels ----
    v2f inv; inv.x = 1.0f / sw.x; inv.y = 1.0f / sw.y;
    v2f mx = swx * inv, my = swy * inv;
    v2f varx = vfma(-mx, mx, swxx * inv);
    v2f cov  = vfma(-mx, my, swxy * inv);
    v2f A; A.x = cov.x / (varx.x + 1e-6f); A.y = cov.y / (varx.y + 1e-6f);
    v2f b = my - A * mx;
    v2f bd; bd.x = sv.x / swd.x; bd.y = sv.y / swd.y;
    v2f res = A * Xc2 + b + Xd2 + bd;
    out[p0]     = res.x;
    out[p0 + W] = res.y;
}

extern "C" void kernel_launch(void* const* d_in, const int* in_sizes, int n_in,
                              void* d_out, int out_size, void* d_ws, size_t ws_size,
                              hipStream_t stream) {
    const float* X = (const float*)d_in[0];
    const float* y = (const float*)d_in[1];
    const float* r = (const float*)d_in[2];
    float* out = (float*)d_out;
    float* wsf = (float*)d_ws;

    float2* partial = (float2*)(wsf + 64);                 // 512 float2
    float2* XYb = (float2*)(wsf + 4096) + 256;             // guarded
    float2* XDd = XYb + NPIX + 512;                        // guarded

    k_prep<<<dim3(8, 64), dim3(64, 8), 0, stream>>>(X, y, XYb, XDd, partial);
    k_main<<<dim3(8, 64), dim3(64, 4), 0, stream>>>(XYb, XDd, partial, r, out);
}

// Round 6
// 92.067 us; speedup vs baseline: 1.9961x; 1.0043x over previous
//
#include <hip/hip_runtime.h>

#define W 512

typedef float v2f __attribute__((ext_vector_type(2)));

__device__ __forceinline__ float fexp2(float x) {
#if __has_builtin(__builtin_amdgcn_exp2f)
    return __builtin_amdgcn_exp2f(x);
#else
    return __expf(x * 0.6931471805599453f);
#endif
}
__device__ __forceinline__ v2f vfma(v2f a, v2f b, v2f c) {
    return __builtin_elementwise_fma(a, b, c);
}
__device__ __forceinline__ v2f bc2(float x) { v2f r; r.x = x; r.y = x; return r; }

// ---------------- tiny min/max pre-pass: 256 contention-free partials ----------------
__global__ __launch_bounds__(256) void k_minmax(const float* __restrict__ y,
                                                float2* __restrict__ partial) {
    __shared__ float smn[256], smx[256];
    int t = threadIdx.x;
    const float4* y4 = (const float4*)y;
    float4 v = y4[blockIdx.x * 256 + t];
    float mn = fminf(fminf(v.x, v.y), fminf(v.z, v.w));
    float mx = fmaxf(fmaxf(v.x, v.y), fmaxf(v.z, v.w));
    smn[t] = mn; smx[t] = mx;
    __syncthreads();
    for (int off = 128; off > 0; off >>= 1) {
        if (t < off) {
            smn[t] = fminf(smn[t], smn[t + off]);
            smx[t] = fmaxf(smx[t], smx[t + off]);
        }
        __syncthreads();
    }
    if (t == 0) partial[blockIdx.x] = make_float2(smn[0], smx[0]);
}

// ---------------- fully fused kernel: box + bilateral, all tiles LDS-resident ----
// Block: 64x4 threads, 2 vertical px/thread -> 64 cols x 8 rows output tile.
__global__ __launch_bounds__(256) void k_fused(const float* __restrict__ X,
                                               const float* __restrict__ y,
                                               const float2* __restrict__ partial,
                                               const float* __restrict__ r,
                                               float* __restrict__ out) {
    __shared__ float sbx[19];   // row spatial weights, 19x19 filter
    __shared__ float sdy[5];    // row spatial weights, 5x9 filter
    // one LDS arena with phase-based aliasing (60256 B < 64 KB static limit)
    __shared__ __align__(16) char ldsbuf[60256];
    float*  sX  = (float*)ldsbuf;            // 34*90 staged X   (rows r0-13..r0+20, cols c0-13..c0+76)
    float*  sY  = sX + 34 * 90;              // 34*90 staged y
    float*  csX = sY + 34 * 90;              // 26*90 9-row col-sums of X
    float*  csY = csX + 26 * 90;             // 26*90
    float2* bXY = (float2*)(csY + 26 * 90);  // 26*82 (Xb,yb)    (rows r0-9..r0+16, cols c0-9..c0+72)
    float2* dXD = (float2*)csX;              // 12*72 (Xd,Dd) — aliases cs after it's dead
    float2* red = (float2*)sX;               // 256 — prologue alias, dead before staging

    int tx = threadIdx.x, ty = threadIdx.y;
    int t = ty * 64 + tx;
    int c0 = blockIdx.x * 64, r0 = blockIdx.y * 8;

    if (t < 19)      { int d = t - 9;      sbx[t]      = __expf(-(float)(d * d) / 8145.0625f); }
    else if (t < 24) { int d = t - 19 - 2; sdy[t - 19] = __expf(-(float)(d * d) / 126.5625f); }

    // ---- prologue: reduce 256 min/max partials -> k2 ----
    red[t] = partial[t];
    __syncthreads();
    for (int off = 128; off > 0; off >>= 1) {
        if (t < off) {
            red[t].x = fminf(red[t].x, red[t + off].x);
            red[t].y = fmaxf(red[t].y, red[t + off].y);
        }
        __syncthreads();
    }
    float2 mm0 = red[0];
    __syncthreads();                          // red (sX alias) free for staging
    float sigma = r[0] * (mm0.y - mm0.x);
    float hh = 0.5f * sigma;
    float k2 = -1.4426950408889634f / (hh * hh);   // w_range = 2^(u^2*k2)
    v2f k2v = bc2(k2);

    // ---- stage X,y with halo (zero outside image) ----
    for (int i = t; i < 34 * 90; i += 256) {
        int rr = i / 90, cc2 = i - rr * 90;
        int gr = r0 - 13 + rr, gc = c0 - 13 + cc2;
        bool ok = ((unsigned)gr < 512u) & ((unsigned)gc < 512u);
        float xv = 0.f, yv = 0.f;
        if (ok) { xv = X[gr * W + gc]; yv = y[gr * W + gc]; }
        sX[i] = xv; sY[i] = yv;
    }
    __syncthreads();

    // ---- 9-row column sums ----
    for (int i = t; i < 26 * 90; i += 256) {
        int rr = i / 90, cc2 = i - rr * 90;
        float ax = 0.f, ay = 0.f;
#pragma unroll
        for (int k = 0; k < 9; ++k) { ax += sX[(rr + k) * 90 + cc2]; ay += sY[(rr + k) * 90 + cc2]; }
        csX[i] = ax; csY[i] = ay;
    }
    __syncthreads();

    // ---- 9-col sums -> (Xb, yb) tile ----
    const float inv81 = 1.0f / 81.0f;
    for (int i = t; i < 26 * 82; i += 256) {
        int rr = i / 82, cc2 = i - rr * 82;
        float ax = 0.f, ay = 0.f;
#pragma unroll
        for (int k = 0; k < 9; ++k) { ax += csX[rr * 90 + cc2 + k]; ay += csY[rr * 90 + cc2 + k]; }
        bXY[i] = make_float2(ax * inv81, ay * inv81);
    }
    __syncthreads();

    // ---- (Xd, Dd) detail tile (rows r0-2..r0+9, cols c0-4..c0+67); aliases cs ----
    for (int i = t; i < 12 * 72; i += 256) {
        int rr = i / 72, cc2 = i - rr * 72;
        float2 b2 = bXY[(rr + 7) * 82 + (cc2 + 5)];
        float xc = sX[(rr + 11) * 90 + (cc2 + 9)];
        float yc = sY[(rr + 11) * 90 + (cc2 + 9)];
        float xd = xc - b2.x;
        dXD[i] = make_float2(xd, (yc - b2.y) - xd);
    }
    __syncthreads();

    // ---- bilateral passes (all LDS reads) ----
    int c  = blockIdx.x * 64 + tx;
    int h0 = r0 + ty * 2;                      // rows h0, h0+1

    // chunk mapping: output col -> owning chunk after overlap-trim
    int chunk = (c == 0) ? 0 : (c - 1) / 62;
    if (chunk > 8) chunk = 8;
    int s = 62 * chunk;
    int e = (chunk == 8) ? 512 : (s + 64);

    // column exponents (log2-domain spatial) with chunk mask folded in
    const float ksb = -1.4426950408889634f / 8145.0625f;
    const float ksd = -1.4426950408889634f / 126.5625f;
    float cc[19];
#pragma unroll
    for (int j = 0; j < 19; ++j) {
        int nc = c - 9 + j, d = j - 9;
        cc[j] = ((nc >= s) & (nc < e)) ? ksb * (float)(d * d) : -1e30f;
    }
    float ccd[9];
#pragma unroll
    for (int j = 0; j < 9; ++j) {
        int nc = c - 4 + j, d = j - 4;
        ccd[j] = ((nc >= s) & (nc < e)) ? ksd * (float)(d * d) : -1e30f;
    }

    v2f Xc2; Xc2.x = bXY[(2 * ty + 9)  * 82 + tx + 9].x;
             Xc2.y = bXY[(2 * ty + 10) * 82 + tx + 9].x;
    v2f Xd2; Xd2.x = dXD[(2 * ty + 2) * 72 + tx + 4].x;
             Xd2.y = dXD[(2 * ty + 3) * 72 + tx + 4].x;

    // ---- base pass: 19x19 bilateral guided-filter stats, packed 2 px ----
    v2f sw = bc2(0.f), swx = bc2(0.f), swy = bc2(0.f), swxx = bc2(0.f), swxy = bc2(0.f);
#pragma unroll 1
    for (int nh = h0 - 9; nh <= h0 + 10; ++nh) {
        if ((unsigned)nh >= 512u) continue;          // wave-uniform
        int dy0 = nh - h0;                           // -9..10
        const float2* xr = bXY + (nh - r0 + 9) * 82 + tx;
        v2f rs = bc2(0.f), rsx = bc2(0.f), rsy = bc2(0.f), rsxx = bc2(0.f), rsxy = bc2(0.f);
#pragma unroll
        for (int j = 0; j < 19; ++j) {
            float2 v = xr[j];
            v2f xv = bc2(v.x), yv = bc2(v.y);
            v2f u = xv - Xc2;
            v2f a = vfma(u * k2v, u, bc2(cc[j]));
            v2f w; w.x = fexp2(a.x); w.y = fexp2(a.y);
            rs = rs + w;
            rsx = vfma(w, xv, rsx);
            rsy = vfma(w, yv, rsy);
            v2f tt = w * xv;
            rsxx = vfma(tt, xv, rsxx);
            rsxy = vfma(tt, yv, rsxy);
        }
        v2f ey;
        ey.x = (dy0 <= 9)  ? sbx[dy0 + 9] : 0.f;
        ey.y = (dy0 >= -8) ? sbx[dy0 + 8] : 0.f;
        sw   = vfma(ey, rs,   sw);
        swx  = vfma(ey, rsx,  swx);
        swy  = vfma(ey, rsy,  swy);
        swxx = vfma(ey, rsxx, swxx);
        swxy = vfma(ey, rsxy, swxy);
    }

    // ---- detail pass: 5(h)x9(w) bilateral on residuals, packed 2 px ----
    v2f swd = bc2(0.f), sv = bc2(0.f);
#pragma unroll 1
    for (int nh = h0 - 2; nh <= h0 + 3; ++nh) {
        if ((unsigned)nh >= 512u) continue;
        int dyd = nh - h0;                           // -2..3
        const float2* dr2 = dXD + (nh - r0 + 2) * 72 + tx;
        v2f rs = bc2(0.f), rv = bc2(0.f);
#pragma unroll
        for (int j = 0; j < 9; ++j) {
            float2 v = dr2[j];
            v2f xd = bc2(v.x), dv = bc2(v.y);
            v2f u = xd - Xd2;
            v2f a = vfma(u * k2v, u, bc2(ccd[j]));
            v2f w; w.x = fexp2(a.x); w.y = fexp2(a.y);
            rs = rs + w;
            rv = vfma(w, dv, rv);
        }
        v2f ey;
        ey.x = (dyd <= 2)  ? sdy[dyd + 2] : 0.f;
        ey.y = (dyd >= -1) ? sdy[dyd + 1] : 0.f;
        swd = vfma(ey, rs, swd);
        sv  = vfma(ey, rv, sv);
    }

    // ---- combine & store both pixels ----
    v2f inv; inv.x = 1.0f / sw.x; inv.y = 1.0f / sw.y;
    v2f mx = swx * inv, my = swy * inv;
    v2f varx = vfma(-mx, mx, swxx * inv);
    v2f cov  = vfma(-mx, my, swxy * inv);
    v2f A; A.x = cov.x / (varx.x + 1e-6f); A.y = cov.y / (varx.y + 1e-6f);
    v2f b = my - A * mx;
    v2f bd; bd.x = sv.x / swd.x; bd.y = sv.y / swd.y;
    v2f res = A * Xc2 + b + Xd2 + bd;
    int p0 = h0 * W + c;
    out[p0]     = res.x;
    out[p0 + W] = res.y;
}

extern "C" void kernel_launch(void* const* d_in, const int* in_sizes, int n_in,
                              void* d_out, int out_size, void* d_ws, size_t ws_size,
                              hipStream_t stream) {
    const float* X = (const float*)d_in[0];
    const float* y = (const float*)d_in[1];
    const float* r = (const float*)d_in[2];
    float* out = (float*)d_out;
    float2* partial = (float2*)d_ws;               // 256 float2, fully written each call

    k_minmax<<<256, 256, 0, stream>>>(y, partial);
    k_fused<<<dim3(8, 64), dim3(64, 4), 0, stream>>>(X, y, partial, r, out);
}